// Round 2
// baseline (14092.551 us; speedup 1.0000x reference)
//
#include <hip/hip_runtime.h>

// Problem dims
#define BB   64
#define PP   196
#define ENC  2048
#define AA   512
#define EE   512
#define DD   512
#define VV   20000
#define TT   21
#define ML   22

#define PRED_ELEMS ((size_t)BB * TT * VV)   // 26,880,000

__device__ __forceinline__ float bf2f(unsigned short u) {
    union { unsigned int i; float f; } v;
    v.i = ((unsigned int)u) << 16;
    return v.f;
}

__device__ __forceinline__ void unpack2(unsigned int u, float& lo, float& hi) {
    union { unsigned int i; float f; } a, b;
    a.i = u << 16;          // low ushort -> float
    b.i = u & 0xFFFF0000u;  // high ushort -> float
    lo = a.f; hi = b.f;
}

__device__ __forceinline__ unsigned short f2bf(float f) {
    union { float f; unsigned int i; } v;
    v.f = f;
    unsigned int i = v.i;
    return (unsigned short)((i + 0x7FFFu + ((i >> 16) & 1u)) >> 16); // RNE
}

__device__ __forceinline__ float sigmoidf(float x) {
    return 1.0f / (1.0f + __expf(-x));
}

// ---- dtype-polymorphic load/store helpers (F = true -> float32 buffers) ----
template <bool F>
__device__ __forceinline__ float ldw(const void* p, size_t i) {
    if (F) return ((const float*)p)[i];
    return bf2f(((const unsigned short*)p)[i]);
}
template <bool F>
__device__ __forceinline__ float2 ld2(const void* p, size_t i) {   // i must be even
    if (F) return *(const float2*)((const float*)p + i);
    unsigned int u = *(const unsigned int*)((const unsigned short*)p + i);
    float lo, hi; unpack2(u, lo, hi);
    return make_float2(lo, hi);
}
template <bool F>
__device__ __forceinline__ float4 ld4(const void* p, size_t i) {   // i % 4 == 0
    if (F) return *(const float4*)((const float*)p + i);
    uint2 u = *(const uint2*)((const unsigned short*)p + i);
    float a, b, c, d; unpack2(u.x, a, b); unpack2(u.y, c, d);
    return make_float4(a, b, c, d);
}
template <bool F>
__device__ __forceinline__ void st1(void* p, size_t i, float v) {
    if (F) ((float*)p)[i] = v; else ((unsigned short*)p)[i] = f2bf(v);
}
template <bool F>
__device__ __forceinline__ void st4(void* p, size_t i, float a, float b, float c, float d) {
    if (F) { *(float4*)((float*)p + i) = make_float4(a, b, c, d); }
    else {
        ushort4 r; r.x = f2bf(a); r.y = f2bf(b); r.z = f2bf(c); r.w = f2bf(d);
        *(ushort4*)((unsigned short*)p + i) = r;
    }
}

// ---------------- dtype detector ----------------
// If encoder_out is f32, its even-indexed ushorts are mantissa fragments:
// ~0.4% decode as bf16 inf/NaN ((u&0x7F80)==0x7F80). If it is bf16 (randn
// values), no element is inf/NaN. Scan 8192 even ushorts -> flag.
__global__ void dec_detect_kernel(const unsigned short* __restrict__ enc_us, int* __restrict__ flag) {
    __shared__ int s_cnt;
    if (threadIdx.x == 0) s_cnt = 0;
    __syncthreads();
    int cnt = 0;
    for (int i = threadIdx.x; i < 8192; i += 256) {
        unsigned short u = enc_us[2 * i];
        if ((u & 0x7F80) == 0x7F80) cnt++;
    }
    if (cnt) atomicAdd(&s_cnt, cnt);
    __syncthreads();
    if (threadIdx.x == 0) *flag = (s_cnt > 0) ? 1 : 0;
}

// ---------------- setup kernels ----------------

template <bool F>
__device__ __forceinline__ void mean_body(const void* enc, float* mean) {
    int b = blockIdx.x;
    int e = blockIdx.y * 256 + threadIdx.x;           // grid (64,8), block 256
    size_t base = (size_t)b * PP * ENC + e;
    float s = 0.f;
#pragma unroll 4
    for (int p = 0; p < PP; ++p) s += ldw<F>(enc, base + (size_t)p * ENC);
    mean[b * ENC + e] = s * (1.0f / (float)PP);
}
__global__ void dec_mean_kernel(const void* __restrict__ enc, const int* __restrict__ flg,
                                float* __restrict__ mean) {
    if (*flg) mean_body<true>(enc, mean); else mean_body<false>(enc, mean);
}

template <bool F>
__device__ __forceinline__ void init_body(const float* mean, const void* ihw, const void* ihb,
                                          const void* icw, const void* icb, float* h, float* c) {
    __shared__ float s_m[ENC];
    int b = blockIdx.x, tid = threadIdx.x;            // block 512
    for (int k = tid; k < ENC; k += 512) s_m[k] = mean[b * ENC + k];
    __syncthreads();
    float ah = ldw<F>(ihb, tid), ac = ldw<F>(icb, tid);
#pragma unroll 4
    for (int k = 0; k < ENC; ++k) {
        float m = s_m[k];
        ah += m * ldw<F>(ihw, (size_t)k * DD + tid);
        ac += m * ldw<F>(icw, (size_t)k * DD + tid);
    }
    h[b * DD + tid] = ah;
    c[b * DD + tid] = ac;
}
__global__ void dec_init_kernel(const float* __restrict__ mean, const int* __restrict__ flg,
                                const void* __restrict__ ihw, const void* __restrict__ ihb,
                                const void* __restrict__ icw, const void* __restrict__ icb,
                                float* __restrict__ h, float* __restrict__ c) {
    if (*flg) init_body<true>(mean, ihw, ihb, icw, icb, h, c);
    else      init_body<false>(mean, ihw, ihb, icw, icb, h, c);
}

template <bool F>
__device__ __forceinline__ void att1_body(const void* enc, const void* w, const void* bias,
                                          float* att1) {
    __shared__ float s_row[ENC];
    int row = blockIdx.x, tid = threadIdx.x;          // grid 12544, block 256
    for (int k = tid; k < ENC; k += 256) s_row[k] = ldw<F>(enc, (size_t)row * ENC + k);
    __syncthreads();
    int a0 = tid * 2;
    float2 bi = ld2<F>(bias, a0);
    float acc0 = bi.x, acc1 = bi.y;
#pragma unroll 4
    for (int k = 0; k < ENC; ++k) {
        float2 wv = ld2<F>(w, (size_t)k * AA + a0);
        float rv = s_row[k];
        acc0 += rv * wv.x; acc1 += rv * wv.y;
    }
    att1[(size_t)row * AA + a0]     = acc0;
    att1[(size_t)row * AA + a0 + 1] = acc1;
}
__global__ void dec_att1_kernel(const void* __restrict__ enc, const int* __restrict__ flg,
                                const void* __restrict__ w, const void* __restrict__ bias,
                                float* __restrict__ att1) {
    if (*flg) att1_body<true>(enc, w, bias, att1); else att1_body<false>(enc, w, bias, att1);
}

// ---------------- per-step kernels ----------------

template <bool F>
__device__ __forceinline__ void att_body(const float* att1, const float* h,
                                         const void* daw, const void* dab,
                                         const void* faw, const void* fab,
                                         const int* lengths, float* alpha_ws, void* out, int t) {
    __shared__ float s_h[DD];
    __shared__ float s_att2[AA];
    __shared__ float s_fw[AA];
    __shared__ float s_red[256];
    int b = blockIdx.x, tid = threadIdx.x;            // grid 64, block 256
    for (int d = tid; d < DD; d += 256) { s_h[d] = h[b * DD + d]; s_fw[d] = ldw<F>(faw, d); }
    __syncthreads();
    {
        int a0 = tid * 2;
        float2 bi = ld2<F>(dab, a0);
        float acc0 = bi.x, acc1 = bi.y;
#pragma unroll 4
        for (int d = 0; d < DD; ++d) {
            float2 wv = ld2<F>(daw, (size_t)d * AA + a0);
            float hv = s_h[d];
            acc0 += hv * wv.x; acc1 += hv * wv.y;
        }
        s_att2[a0] = acc0; s_att2[a0 + 1] = acc1;
    }
    __syncthreads();
    float sc = -1e30f;
    if (tid < PP) {
        const float4* r = (const float4*)(att1 + (size_t)(b * PP + tid) * AA);
        float acc = 0.f;
#pragma unroll 4
        for (int a4 = 0; a4 < AA / 4; ++a4) {
            float4 v = r[a4];
            int a = a4 * 4;
            acc += fmaxf(v.x + s_att2[a], 0.f)     * s_fw[a]
                 + fmaxf(v.y + s_att2[a + 1], 0.f) * s_fw[a + 1]
                 + fmaxf(v.z + s_att2[a + 2], 0.f) * s_fw[a + 2]
                 + fmaxf(v.w + s_att2[a + 3], 0.f) * s_fw[a + 3];
        }
        sc = acc + ldw<F>(fab, 0);
    }
    s_red[tid] = sc;
    __syncthreads();
    for (int s = 128; s > 0; s >>= 1) { if (tid < s) s_red[tid] = fmaxf(s_red[tid], s_red[tid + s]); __syncthreads(); }
    float m = s_red[0];
    __syncthreads();
    float e = 0.f;
    if (tid < PP) e = __expf(sc - m);
    s_red[tid] = e;
    __syncthreads();
    for (int s = 128; s > 0; s >>= 1) { if (tid < s) s_red[tid] += s_red[tid + s]; __syncthreads(); }
    float inv = 1.0f / s_red[0];
    if (tid < PP) {
        float al = e * inv;
        alpha_ws[b * PP + tid] = al;
        bool active = t < (lengths[b] - 1);
        st1<F>(out, PRED_ELEMS + (size_t)(b * TT + t) * PP + tid, active ? al : 0.f);
    }
}
__global__ void dec_att_kernel(const float* __restrict__ att1, const float* __restrict__ h,
                               const int* __restrict__ flg,
                               const void* __restrict__ daw, const void* __restrict__ dab,
                               const void* __restrict__ faw, const void* __restrict__ fab,
                               const int* __restrict__ lengths,
                               float* __restrict__ alpha_ws, void* __restrict__ out, int t) {
    if (*flg) att_body<true>(att1, h, daw, dab, faw, fab, lengths, alpha_ws, out, t);
    else      att_body<false>(att1, h, daw, dab, faw, fab, lengths, alpha_ws, out, t);
}

template <bool F>
__device__ __forceinline__ void ctx_body(const void* enc, const float* alpha_ws, const float* h,
                                         const void* fbw, const void* fbb,
                                         const void* emb, const int* captions, float* x, int t) {
    __shared__ float s_al[PP];
    __shared__ float s_h[DD];
    int b = blockIdx.x, tid = threadIdx.x;            // grid (64,8), block 256
    if (tid < PP) s_al[tid] = alpha_ws[b * PP + tid];
    for (int d = tid; d < DD; d += 256) s_h[d] = h[b * DD + d];
    __syncthreads();
    if (blockIdx.y == 0) {
        int cap = captions[b * ML + t];
        for (int i = tid; i < EE; i += 256) x[b * 2560 + i] = ldw<F>(emb, (size_t)cap * EE + i);
    }
    int e = blockIdx.y * 256 + tid;
    size_t ebase = (size_t)b * PP * ENC + e;
    float ctx = 0.f;
#pragma unroll 4
    for (int p = 0; p < PP; ++p) ctx += s_al[p] * ldw<F>(enc, ebase + (size_t)p * ENC);
    float g = ldw<F>(fbb, e);
#pragma unroll 4
    for (int d = 0; d < DD; ++d) g += s_h[d] * ldw<F>(fbw, (size_t)d * ENC + e);
    g = sigmoidf(g);
    x[b * 2560 + EE + e] = g * ctx;
}
__global__ void dec_ctx_kernel(const void* __restrict__ enc, const float* __restrict__ alpha_ws,
                               const float* __restrict__ h, const int* __restrict__ flg,
                               const void* __restrict__ fbw, const void* __restrict__ fbb,
                               const void* __restrict__ emb, const int* __restrict__ captions,
                               float* __restrict__ x, int t) {
    if (*flg) ctx_body<true>(enc, alpha_ws, h, fbw, fbb, emb, captions, x, t);
    else      ctx_body<false>(enc, alpha_ws, h, fbw, fbb, emb, captions, x, t);
}

template <bool F>
__device__ __forceinline__ void gates_body(const float* x, const float* h,
                                           const void* w_ih, const void* b_ih,
                                           const void* w_hh, const void* b_hh, float* gates) {
    __shared__ float s_x[2560];
    __shared__ float s_h[DD];
    int b = blockIdx.x, tid = threadIdx.x;            // grid (64,4), block 256
    for (int k = tid; k < 2560; k += 256) s_x[k] = x[b * 2560 + k];
    for (int d = tid; d < DD; d += 256) s_h[d] = h[b * DD + d];
    __syncthreads();
    int j0 = blockIdx.y * 512 + tid * 2;
    float2 bi = ld2<F>(b_ih, j0);
    float2 bh = ld2<F>(b_hh, j0);
    float acc0 = bi.x + bh.x, acc1 = bi.y + bh.y;
#pragma unroll 4
    for (int k = 0; k < 2560; ++k) {
        float2 wv = ld2<F>(w_ih, (size_t)k * 2048 + j0);
        float xv = s_x[k];
        acc0 += xv * wv.x; acc1 += xv * wv.y;
    }
#pragma unroll 4
    for (int d = 0; d < DD; ++d) {
        float2 wv = ld2<F>(w_hh, (size_t)d * 2048 + j0);
        float hv = s_h[d];
        acc0 += hv * wv.x; acc1 += hv * wv.y;
    }
    gates[b * 2048 + j0]     = acc0;
    gates[b * 2048 + j0 + 1] = acc1;
}
__global__ void dec_gates_kernel(const float* __restrict__ x, const float* __restrict__ h,
                                 const int* __restrict__ flg,
                                 const void* __restrict__ w_ih, const void* __restrict__ b_ih,
                                 const void* __restrict__ w_hh, const void* __restrict__ b_hh,
                                 float* __restrict__ gates) {
    if (*flg) gates_body<true>(x, h, w_ih, b_ih, w_hh, b_hh, gates);
    else      gates_body<false>(x, h, w_ih, b_ih, w_hh, b_hh, gates);
}

// LSTM pointwise update (torch gate order i,f,g,o); only active rows update h,c
__global__ void dec_lstm_kernel(const float* __restrict__ gates, float* __restrict__ h, float* __restrict__ c,
                                const int* __restrict__ lengths, int t) {
    int b = blockIdx.x, d = threadIdx.x;              // grid 64, block 512
    if (t >= lengths[b] - 1) return;
    const float* g = gates + b * 2048;
    float ig = sigmoidf(g[d]);
    float fg = sigmoidf(g[DD + d]);
    float gg = tanhf(g[2 * DD + d]);
    float og = sigmoidf(g[3 * DD + d]);
    float cn = fg * c[b * DD + d] + ig * gg;
    float hn = og * tanhf(cn);
    c[b * DD + d] = cn;
    h[b * DD + d] = hn;
}

template <bool F>
__device__ __forceinline__ void preds_body(const float* h, const void* fc_w, const void* fc_b,
                                           const int* lengths, void* out, int t) {
    int b = blockIdx.x, tid = threadIdx.x;            // grid (64,20), block 256
    int idx = blockIdx.y * 256 + tid;
    bool active = t < (lengths[b] - 1);
    size_t obase = (size_t)(b * TT + t) * VV;
    if (!active) {                                    // block-uniform branch
        if (idx < VV / 4) st4<F>(out, obase + (size_t)idx * 4, 0.f, 0.f, 0.f, 0.f);
        return;
    }
    __shared__ float s_h[DD];
    for (int d = tid; d < DD; d += 256) s_h[d] = h[b * DD + d];
    __syncthreads();
    if (idx >= VV / 4) return;
    int v0 = idx * 4;
    float4 bv = ld4<F>(fc_b, v0);
    float a0 = bv.x, a1 = bv.y, a2 = bv.z, a3 = bv.w;
#pragma unroll 4
    for (int d = 0; d < DD; ++d) {
        float4 wv = ld4<F>(fc_w, (size_t)d * VV + v0);
        float hv = s_h[d];
        a0 += hv * wv.x; a1 += hv * wv.y; a2 += hv * wv.z; a3 += hv * wv.w;
    }
    st4<F>(out, obase + v0, a0, a1, a2, a3);
}
__global__ void dec_preds_kernel(const float* __restrict__ h, const int* __restrict__ flg,
                                 const void* __restrict__ fc_w, const void* __restrict__ fc_b,
                                 const int* __restrict__ lengths, void* __restrict__ out, int t) {
    if (*flg) preds_body<true>(h, fc_w, fc_b, lengths, out, t);
    else      preds_body<false>(h, fc_w, fc_b, lengths, out, t);
}

extern "C" void kernel_launch(void* const* d_in, const int* in_sizes, int n_in,
                              void* d_out, int out_size, void* d_ws, size_t ws_size,
                              hipStream_t stream) {
    const void* enc      = d_in[0];
    const int* captions  = (const int*)d_in[1];
    const int* lengths   = (const int*)d_in[2];
    const void* emb      = d_in[3];
    const void* eaw      = d_in[4];
    const void* eab      = d_in[5];
    const void* daw      = d_in[6];
    const void* dab      = d_in[7];
    const void* faw      = d_in[8];
    const void* fab      = d_in[9];
    const void* wih      = d_in[10];
    const void* bih      = d_in[11];
    const void* whh      = d_in[12];
    const void* bhh      = d_in[13];
    const void* ihw      = d_in[14];
    const void* ihb      = d_in[15];
    const void* icw      = d_in[16];
    const void* icb      = d_in[17];
    const void* fbw      = d_in[18];
    const void* fbb      = d_in[19];
    const void* fcw      = d_in[20];
    const void* fcb      = d_in[21];

    // workspace layout: [flag int (256B pad)] then f32 arrays (~27.7 MB)
    int* flg     = (int*)d_ws;
    float* ws_f  = (float*)((char*)d_ws + 256);
    float* h     = ws_f;                    // 64*512
    float* c     = h     + BB * DD;         // 64*512
    float* mean  = c     + BB * DD;         // 64*2048
    float* x     = mean  + BB * ENC;        // 64*2560
    float* gates = x     + BB * 2560;       // 64*2048
    float* alpha = gates + BB * 2048;       // 64*196
    float* att1  = alpha + BB * PP;         // 12544*512

    dec_detect_kernel<<<1, 256, 0, stream>>>((const unsigned short*)enc, flg);
    dec_mean_kernel<<<dim3(BB, ENC / 256), 256, 0, stream>>>(enc, flg, mean);
    dec_init_kernel<<<BB, 512, 0, stream>>>(mean, flg, ihw, ihb, icw, icb, h, c);
    dec_att1_kernel<<<BB * PP, 256, 0, stream>>>(enc, flg, eaw, eab, att1);

    for (int t = 0; t < TT; ++t) {
        dec_att_kernel<<<BB, 256, 0, stream>>>(att1, h, flg, daw, dab, faw, fab, lengths, alpha, d_out, t);
        dec_ctx_kernel<<<dim3(BB, ENC / 256), 256, 0, stream>>>(enc, alpha, h, flg, fbw, fbb, emb, captions, x, t);
        dec_gates_kernel<<<dim3(BB, 4), 256, 0, stream>>>(x, h, flg, wih, bih, whh, bhh, gates);
        dec_lstm_kernel<<<BB, 512, 0, stream>>>(gates, h, c, lengths, t);
        dec_preds_kernel<<<dim3(BB, (VV / 4 + 255) / 256), 256, 0, stream>>>(h, flg, fcw, fcb, lengths, d_out, t);
    }
}

// Round 3
// 5391.143 us; speedup vs baseline: 2.6140x; 2.6140x over previous
//
#include <hip/hip_runtime.h>

#define BB   64
#define PP   196
#define ENC  2048
#define AA   512
#define EE   512
#define DD   512
#define VV   20000
#define TT   21
#define ML   22

#define PRED_ELEMS ((size_t)BB * TT * VV)   // 26,880,000

typedef __attribute__((ext_vector_type(8))) short s8bf;    // 8 bf16 (4 VGPRs)
typedef __attribute__((ext_vector_type(4))) float f4acc;   // 4 fp32 acc

__device__ __forceinline__ float bf2f(unsigned short u) {
    union { unsigned int i; float f; } v; v.i = ((unsigned int)u) << 16; return v.f;
}
__device__ __forceinline__ void unpack2(unsigned int u, float& lo, float& hi) {
    union { unsigned int i; float f; } a, b;
    a.i = u << 16; b.i = u & 0xFFFF0000u; lo = a.f; hi = b.f;
}
__device__ __forceinline__ unsigned short f2bf(float f) {
    union { float f; unsigned int i; } v; v.f = f;
    unsigned int i = v.i;
    return (unsigned short)((i + 0x7FFFu + ((i >> 16) & 1u)) >> 16); // RNE
}
__device__ __forceinline__ float sigmoidf(float x) { return 1.0f / (1.0f + __expf(-x)); }

// ---- dtype-polymorphic helpers (F=true -> f32 buffers, else bf16) ----
template <bool F> __device__ __forceinline__ float ldw(const void* p, size_t i) {
    if (F) return ((const float*)p)[i];
    return bf2f(((const unsigned short*)p)[i]);
}
template <bool F> __device__ __forceinline__ unsigned short ldbf(const void* p, size_t i) {
    if (F) return f2bf(((const float*)p)[i]);   // exact if value already bf16-quantized
    return ((const unsigned short*)p)[i];
}
template <bool F> __device__ __forceinline__ float2 ld2(const void* p, size_t i) {
    if (F) return *(const float2*)((const float*)p + i);
    unsigned int u = *(const unsigned int*)((const unsigned short*)p + i);
    float lo, hi; unpack2(u, lo, hi); return make_float2(lo, hi);
}
template <bool F> __device__ __forceinline__ float4 ld4(const void* p, size_t i) {
    if (F) return *(const float4*)((const float*)p + i);
    uint2 u = *(const uint2*)((const unsigned short*)p + i);
    float a, b, c, d; unpack2(u.x, a, b); unpack2(u.y, c, d);
    return make_float4(a, b, c, d);
}
template <bool F> __device__ __forceinline__ void st1(void* p, size_t i, float v) {
    if (F) ((float*)p)[i] = v; else ((unsigned short*)p)[i] = f2bf(v);
}

// ---------------- dtype detector (f32 words contain bf16-inf/nan patterns) ----------------
__global__ void dec_detect_kernel(const unsigned short* __restrict__ enc_us, int* __restrict__ flag) {
    __shared__ int s_cnt;
    if (threadIdx.x == 0) s_cnt = 0;
    __syncthreads();
    int cnt = 0;
    for (int i = threadIdx.x; i < 8192; i += 256) {
        unsigned short u = enc_us[2 * i];
        if ((u & 0x7F80) == 0x7F80) cnt++;
    }
    if (cnt) atomicAdd(&s_cnt, cnt);
    __syncthreads();
    if (threadIdx.x == 0) *flag = (s_cnt > 0) ? 1 : 0;
}

// ---------------- setup ----------------
template <bool F>
__device__ __forceinline__ void mean_body(const void* enc, float* mean) {
    int b = blockIdx.x;
    int e = blockIdx.y * 256 + threadIdx.x;
    size_t base = (size_t)b * PP * ENC + e;
    float s = 0.f;
#pragma unroll 4
    for (int p = 0; p < PP; ++p) s += ldw<F>(enc, base + (size_t)p * ENC);
    mean[b * ENC + e] = s * (1.0f / (float)PP);
}
__global__ void dec_mean_kernel(const void* __restrict__ enc, const int* __restrict__ flg, float* __restrict__ mean) {
    if (*flg) mean_body<true>(enc, mean); else mean_body<false>(enc, mean);
}

template <bool F>
__device__ __forceinline__ void init_body(const float* mean, const void* ihw, const void* ihb,
                                          const void* icw, const void* icb,
                                          unsigned short* h_bf, float* c) {
    __shared__ float s_m[ENC];
    int b = blockIdx.x, tid = threadIdx.x;            // block 512
    for (int k = tid; k < ENC; k += 512) s_m[k] = mean[b * ENC + k];
    __syncthreads();
    float ah = ldw<F>(ihb, tid), ac = ldw<F>(icb, tid);
#pragma unroll 4
    for (int k = 0; k < ENC; ++k) {
        float m = s_m[k];
        ah += m * ldw<F>(ihw, (size_t)k * DD + tid);
        ac += m * ldw<F>(icw, (size_t)k * DD + tid);
    }
    h_bf[b * DD + tid] = f2bf(ah);
    c[b * DD + tid] = ac;
}
__global__ void dec_init_kernel(const float* __restrict__ mean, const int* __restrict__ flg,
                                const void* __restrict__ ihw, const void* __restrict__ ihb,
                                const void* __restrict__ icw, const void* __restrict__ icb,
                                unsigned short* __restrict__ h_bf, float* __restrict__ c) {
    if (*flg) init_body<true>(mean, ihw, ihb, icw, icb, h_bf, c);
    else      init_body<false>(mean, ihw, ihb, icw, icb, h_bf, c);
}

// ---------------- att1: MFMA GEMM  (M=12544, N=512, K=2048) ----------------
// Block: 256 thr (4 waves). Tile 64 rows x 128 cols; wave -> 2 col-tiles of 16, 4 row-tiles.
// A staged in LDS (f32->bf16 convert), B frags loaded strided from global.
template <bool F>
__device__ __forceinline__ void att1_gemm_body(const void* enc, const void* W, const void* bias,
                                               float* att1) {
    __shared__ __attribute__((aligned(16))) unsigned short As[64 * 40];  // pad 32->40 (bank spread)
    int tid = threadIdx.x;
    int wave = tid >> 6, lane = tid & 63;
    int l15 = lane & 15, quad = lane >> 4;
    int row0 = blockIdx.x * 64;
    int ct0 = blockIdx.y * 128 + wave * 16, ct1 = ct0 + 64;
    f4acc acc[4][2];
#pragma unroll
    for (int a = 0; a < 4; ++a) { acc[a][0] = (f4acc)0.f; acc[a][1] = (f4acc)0.f; }
    int lr = tid >> 2, lk = (tid & 3) * 8;            // staging: thread -> (row, k-oct)
    for (int k0 = 0; k0 < ENC; k0 += 32) {
        // stage A tile 64x32 -> bf16 LDS
        if (F) {
            const float* src = (const float*)enc + (size_t)(row0 + lr) * ENC + k0 + lk;
            float4 v0 = *(const float4*)src, v1 = *(const float4*)(src + 4);
            union { s8bf v; unsigned short s[8]; } t8;
            t8.s[0]=f2bf(v0.x); t8.s[1]=f2bf(v0.y); t8.s[2]=f2bf(v0.z); t8.s[3]=f2bf(v0.w);
            t8.s[4]=f2bf(v1.x); t8.s[5]=f2bf(v1.y); t8.s[6]=f2bf(v1.z); t8.s[7]=f2bf(v1.w);
            *(s8bf*)&As[lr * 40 + lk] = t8.v;
        } else {
            *(s8bf*)&As[lr * 40 + lk] =
                *(const s8bf*)((const unsigned short*)enc + (size_t)(row0 + lr) * ENC + k0 + lk);
        }
        __syncthreads();
        s8bf af[4];
#pragma unroll
        for (int rt = 0; rt < 4; ++rt)
            af[rt] = *(const s8bf*)&As[(rt * 16 + l15) * 40 + quad * 8];
#pragma unroll
        for (int ct = 0; ct < 2; ++ct) {
            int n = (ct ? ct1 : ct0) + l15;
            union { s8bf v; short e[8]; } bu;
            size_t base = (size_t)(k0 + quad * 8) * AA + n;
#pragma unroll
            for (int j = 0; j < 8; ++j) bu.e[j] = (short)ldbf<F>(W, base + (size_t)j * AA);
#pragma unroll
            for (int rt = 0; rt < 4; ++rt)
                acc[rt][ct] = __builtin_amdgcn_mfma_f32_16x16x32_bf16(af[rt], bu.v, acc[rt][ct], 0, 0, 0);
        }
        __syncthreads();
    }
#pragma unroll
    for (int ct = 0; ct < 2; ++ct) {
        int n = (ct ? ct1 : ct0) + l15;
        float bv = ldw<F>(bias, n);
#pragma unroll
        for (int rt = 0; rt < 4; ++rt)
#pragma unroll
            for (int r = 0; r < 4; ++r) {
                int m = row0 + rt * 16 + quad * 4 + r;
                att1[(size_t)m * AA + n] = acc[rt][ct][r] + bv;
            }
    }
}
__global__ __launch_bounds__(256)
void gemm_att1_kernel(const void* __restrict__ enc, const int* __restrict__ flg,
                      const void* __restrict__ W, const void* __restrict__ bias,
                      float* __restrict__ att1) {
    if (*flg) att1_gemm_body<true>(enc, W, bias, att1);
    else      att1_gemm_body<false>(enc, W, bias, att1);
}

// ---------------- generic M=64 MFMA GEMM ----------------
// C[64 x N] = A1[64 x K1] @ W1 (+ A2[64 x K2] @ W2) + biases, epilogue variants.
// A* are bf16 ws mirrors (row-major, stride K). W* row-major [K x N], dtype-F.
// epi: 0 = plain -> outF ; 1 = sigmoid -> outF ; 2 = preds masked -> outV (dtype F)
template <bool F>
__device__ __forceinline__ void gemm_m64_body(const unsigned short* A1, int K1,
                                              const unsigned short* A2, int K2,
                                              const void* W1, const void* W2,
                                              const void* b1, const void* b2,
                                              int N, int epi, float* outF, void* outV,
                                              const int* lengths, int t) {
    int tid = threadIdx.x;
    int wave = tid >> 6, lane = tid & 63;
    int l15 = lane & 15, quad = lane >> 4;
    int ct0 = blockIdx.y * 128 + wave * 16, ct1 = ct0 + 64;
    f4acc acc[4][2];
#pragma unroll
    for (int a = 0; a < 4; ++a) { acc[a][0] = (f4acc)0.f; acc[a][1] = (f4acc)0.f; }
    for (int pass = 0; pass < 2; ++pass) {
        const unsigned short* A = pass ? A2 : A1;
        if (!A) continue;
        int K = pass ? K2 : K1;
        const void* W = pass ? W2 : W1;
        for (int k0 = 0; k0 < K; k0 += 32) {
            s8bf af[4];
#pragma unroll
            for (int rt = 0; rt < 4; ++rt)
                af[rt] = *(const s8bf*)(A + (size_t)(rt * 16 + l15) * K + k0 + quad * 8);
#pragma unroll
            for (int ct = 0; ct < 2; ++ct) {
                int n = (ct ? ct1 : ct0) + l15;
                union { s8bf v; short e[8]; } bu;
                if (n < N) {
                    size_t base = (size_t)(k0 + quad * 8) * N + n;
#pragma unroll
                    for (int j = 0; j < 8; ++j) bu.e[j] = (short)ldbf<F>(W, base + (size_t)j * N);
                } else {
#pragma unroll
                    for (int j = 0; j < 8; ++j) bu.e[j] = 0;
                }
#pragma unroll
                for (int rt = 0; rt < 4; ++rt)
                    acc[rt][ct] = __builtin_amdgcn_mfma_f32_16x16x32_bf16(af[rt], bu.v, acc[rt][ct], 0, 0, 0);
            }
        }
    }
#pragma unroll
    for (int ct = 0; ct < 2; ++ct) {
        int n = (ct ? ct1 : ct0) + l15;
        if (n >= N) continue;
        float bias = b1 ? ldw<F>(b1, n) : 0.f;
        if (b2) bias += ldw<F>(b2, n);
#pragma unroll
        for (int rt = 0; rt < 4; ++rt)
#pragma unroll
            for (int r = 0; r < 4; ++r) {
                int m = rt * 16 + quad * 4 + r;          // m == batch index
                float v = acc[rt][ct][r] + bias;
                if (epi == 0)      outF[(size_t)m * N + n] = v;
                else if (epi == 1) outF[(size_t)m * N + n] = sigmoidf(v);
                else {
                    bool act = t < (lengths[m] - 1);
                    st1<F>(outV, ((size_t)m * TT + t) * VV + n, act ? v : 0.f);
                }
            }
    }
}
__global__ __launch_bounds__(256)
void gemm_m64_kernel(const int* __restrict__ flg,
                     const unsigned short* __restrict__ A1, int K1,
                     const unsigned short* __restrict__ A2, int K2,
                     const void* __restrict__ W1, const void* __restrict__ W2,
                     const void* __restrict__ b1, const void* __restrict__ b2,
                     int N, int epi, float* __restrict__ outF, void* __restrict__ outV,
                     const int* __restrict__ lengths, int t) {
    if (*flg) gemm_m64_body<true>(A1, K1, A2, K2, W1, W2, b1, b2, N, epi, outF, outV, lengths, t);
    else      gemm_m64_body<false>(A1, K1, A2, K2, W1, W2, b1, b2, N, epi, outF, outV, lengths, t);
}

// ---------------- scores + softmax ----------------
template <bool F>
__device__ __forceinline__ void att_body(const float* att1, const float* att2,
                                         const void* faw, const void* fab,
                                         const int* lengths, float* alpha_ws, void* out, int t) {
    __shared__ float s_att2[AA];
    __shared__ float s_fw[AA];
    __shared__ float s_red[256];
    int b = blockIdx.x, tid = threadIdx.x;            // grid 64, block 256
    for (int a = tid; a < AA; a += 256) { s_att2[a] = att2[b * AA + a]; s_fw[a] = ldw<F>(faw, a); }
    __syncthreads();
    float sc = -1e30f;
    if (tid < PP) {
        const float4* r = (const float4*)(att1 + (size_t)(b * PP + tid) * AA);
        float acc = 0.f;
#pragma unroll 4
        for (int a4 = 0; a4 < AA / 4; ++a4) {
            float4 v = r[a4];
            int a = a4 * 4;
            acc += fmaxf(v.x + s_att2[a], 0.f)     * s_fw[a]
                 + fmaxf(v.y + s_att2[a + 1], 0.f) * s_fw[a + 1]
                 + fmaxf(v.z + s_att2[a + 2], 0.f) * s_fw[a + 2]
                 + fmaxf(v.w + s_att2[a + 3], 0.f) * s_fw[a + 3];
        }
        sc = acc + ldw<F>(fab, 0);
    }
    s_red[tid] = sc;
    __syncthreads();
    for (int s = 128; s > 0; s >>= 1) { if (tid < s) s_red[tid] = fmaxf(s_red[tid], s_red[tid + s]); __syncthreads(); }
    float m = s_red[0];
    __syncthreads();
    float e = 0.f;
    if (tid < PP) e = __expf(sc - m);
    s_red[tid] = e;
    __syncthreads();
    for (int s = 128; s > 0; s >>= 1) { if (tid < s) s_red[tid] += s_red[tid + s]; __syncthreads(); }
    float inv = 1.0f / s_red[0];
    if (tid < PP) {
        float al = e * inv;
        alpha_ws[b * PP + tid] = al;
        bool active = t < (lengths[b] - 1);
        st1<F>(out, PRED_ELEMS + (size_t)(b * TT + t) * PP + tid, active ? al : 0.f);
    }
}
__global__ void dec_att_kernel(const float* __restrict__ att1, const float* __restrict__ att2,
                               const int* __restrict__ flg,
                               const void* __restrict__ faw, const void* __restrict__ fab,
                               const int* __restrict__ lengths,
                               float* __restrict__ alpha_ws, void* __restrict__ out, int t) {
    if (*flg) att_body<true>(att1, att2, faw, fab, lengths, alpha_ws, out, t);
    else      att_body<false>(att1, att2, faw, fab, lengths, alpha_ws, out, t);
}

// ---------------- context: coalesced partial sums over p ----------------
template <bool F>
__device__ __forceinline__ void ctx_partial_body(const void* enc, const float* alpha_ws, float* partial) {
    __shared__ float s_al[PP];
    int b = blockIdx.x, half = blockIdx.y, pc = blockIdx.z, tid = threadIdx.x; // grid (64,2,4)
    if (tid < PP) s_al[tid] = alpha_ws[b * PP + tid];
    __syncthreads();
    int e = half * 1024 + tid * 4;
    float a0 = 0.f, a1 = 0.f, a2 = 0.f, a3 = 0.f;
    int p0 = pc * 49;
#pragma unroll 4
    for (int p = p0; p < p0 + 49; ++p) {
        float al = s_al[p];
        float4 v = ld4<F>(enc, (size_t)(b * PP + p) * ENC + e);
        a0 += al * v.x; a1 += al * v.y; a2 += al * v.z; a3 += al * v.w;
    }
    *(float4*)&partial[(size_t)(b * 4 + pc) * ENC + e] = make_float4(a0, a1, a2, a3);
}
__global__ void dec_ctx_partial_kernel(const void* __restrict__ enc, const int* __restrict__ flg,
                                       const float* __restrict__ alpha_ws, float* __restrict__ partial) {
    if (*flg) ctx_partial_body<true>(enc, alpha_ws, partial);
    else      ctx_partial_body<false>(enc, alpha_ws, partial);
}

// reduce partials, apply gate, assemble x_bf = [emb | gate*ctx] (bf16)
template <bool F>
__device__ __forceinline__ void ctx_reduce_body(const float* partial, const float* gate,
                                                const void* emb, const int* captions,
                                                unsigned short* x_bf, int t) {
    int b = blockIdx.x, half = blockIdx.y, tid = threadIdx.x;  // grid (64,2), block 256
    if (half == 0) {  // embedding half-copy handled by y==0 blocks
        int cap = captions[b * ML + t];
        int i = tid * 2;
        float2 ev = ld2<F>(emb, (size_t)cap * EE + i);
        *(unsigned int*)(x_bf + (size_t)b * 2560 + i) =
            (unsigned int)f2bf(ev.x) | ((unsigned int)f2bf(ev.y) << 16);
    }
    int e = half * 1024 + tid * 4;
    float4 s = *(const float4*)&partial[(size_t)(b * 4 + 0) * ENC + e];
#pragma unroll
    for (int pc = 1; pc < 4; ++pc) {
        float4 v = *(const float4*)&partial[(size_t)(b * 4 + pc) * ENC + e];
        s.x += v.x; s.y += v.y; s.z += v.z; s.w += v.w;
    }
    float4 g = *(const float4*)&gate[(size_t)b * ENC + e];
    uint2 pk;
    pk.x = (unsigned int)f2bf(s.x * g.x) | ((unsigned int)f2bf(s.y * g.y) << 16);
    pk.y = (unsigned int)f2bf(s.z * g.z) | ((unsigned int)f2bf(s.w * g.w) << 16);
    *(uint2*)(x_bf + (size_t)b * 2560 + EE + e) = pk;
}
__global__ void dec_ctx_reduce_kernel(const float* __restrict__ partial, const float* __restrict__ gate,
                                      const int* __restrict__ flg,
                                      const void* __restrict__ emb, const int* __restrict__ captions,
                                      unsigned short* __restrict__ x_bf, int t) {
    if (*flg) ctx_reduce_body<true>(partial, gate, emb, captions, x_bf, t);
    else      ctx_reduce_body<false>(partial, gate, emb, captions, x_bf, t);
}

// ---------------- LSTM pointwise ----------------
__global__ void dec_lstm_kernel(const float* __restrict__ gates, unsigned short* __restrict__ h_bf,
                                float* __restrict__ c, const int* __restrict__ lengths, int t) {
    int b = blockIdx.x, d = threadIdx.x;              // grid 64, block 512
    if (t >= lengths[b] - 1) return;
    const float* g = gates + (size_t)b * 2048;
    float ig = sigmoidf(g[d]);
    float fg = sigmoidf(g[DD + d]);
    float gg = tanhf(g[2 * DD + d]);
    float og = sigmoidf(g[3 * DD + d]);
    float cn = fg * c[b * DD + d] + ig * gg;
    float hn = og * tanhf(cn);
    c[b * DD + d] = cn;
    h_bf[b * DD + d] = f2bf(hn);
}

extern "C" void kernel_launch(void* const* d_in, const int* in_sizes, int n_in,
                              void* d_out, int out_size, void* d_ws, size_t ws_size,
                              hipStream_t stream) {
    const void* enc      = d_in[0];
    const int* captions  = (const int*)d_in[1];
    const int* lengths   = (const int*)d_in[2];
    const void* emb      = d_in[3];
    const void* eaw      = d_in[4];
    const void* eab      = d_in[5];
    const void* daw      = d_in[6];
    const void* dab      = d_in[7];
    const void* faw      = d_in[8];
    const void* fab      = d_in[9];
    const void* wih      = d_in[10];
    const void* bih      = d_in[11];
    const void* whh      = d_in[12];
    const void* bhh      = d_in[13];
    const void* ihw      = d_in[14];
    const void* ihb      = d_in[15];
    const void* icw      = d_in[16];
    const void* icb      = d_in[17];
    const void* fbw      = d_in[18];
    const void* fbb      = d_in[19];
    const void* fcw      = d_in[20];
    const void* fcb      = d_in[21];

    // workspace layout (~30 MB), 256B-aligned segments
    char* cur = (char*)d_ws;
    auto alloc = [&](size_t bytes) { void* p = cur; cur += (bytes + 255) & ~(size_t)255; return p; };
    int* flg               = (int*)alloc(4);
    unsigned short* h_bf   = (unsigned short*)alloc((size_t)BB * DD * 2);
    unsigned short* x_bf   = (unsigned short*)alloc((size_t)BB * 2560 * 2);
    float* c               = (float*)alloc((size_t)BB * DD * 4);
    float* mean            = (float*)alloc((size_t)BB * ENC * 4);
    float* att2            = (float*)alloc((size_t)BB * AA * 4);
    float* gate            = (float*)alloc((size_t)BB * ENC * 4);
    float* gates           = (float*)alloc((size_t)BB * 2048 * 4);
    float* alpha           = (float*)alloc((size_t)BB * PP * 4);
    float* partial         = (float*)alloc((size_t)BB * 4 * ENC * 4);
    float* att1            = (float*)alloc((size_t)BB * PP * AA * 4);

    dec_detect_kernel<<<1, 256, 0, stream>>>((const unsigned short*)enc, flg);
    dec_mean_kernel<<<dim3(BB, ENC / 256), 256, 0, stream>>>(enc, flg, mean);
    dec_init_kernel<<<BB, 512, 0, stream>>>(mean, flg, ihw, ihb, icw, icb, h_bf, c);
    gemm_att1_kernel<<<dim3(196, 4), 256, 0, stream>>>(enc, flg, eaw, eab, att1);

    for (int t = 0; t < TT; ++t) {
        // att2 = h @ dec_att_w + dab : (64, 512)
        gemm_m64_kernel<<<dim3(1, 4), 256, 0, stream>>>(flg, h_bf, DD, nullptr, 0,
                                                        daw, nullptr, dab, nullptr,
                                                        AA, 0, att2, nullptr, nullptr, 0);
        // scores + softmax -> alpha (+ alphas output)
        dec_att_kernel<<<BB, 256, 0, stream>>>(att1, att2, flg, faw, fab, lengths, alpha, d_out, t);
        // gate = sigmoid(h @ f_beta + fbb) : (64, 2048)
        gemm_m64_kernel<<<dim3(1, 16), 256, 0, stream>>>(flg, h_bf, DD, nullptr, 0,
                                                         fbw, nullptr, fbb, nullptr,
                                                         ENC, 1, gate, nullptr, nullptr, 0);
        // context partial sums + reduce/assemble x
        dec_ctx_partial_kernel<<<dim3(BB, 2, 4), 256, 0, stream>>>(enc, flg, alpha, partial);
        dec_ctx_reduce_kernel<<<dim3(BB, 2), 256, 0, stream>>>(partial, gate, flg, emb, captions, x_bf, t);
        // gates = x @ w_ih + h @ w_hh + b_ih + b_hh : (64, 2048)
        gemm_m64_kernel<<<dim3(1, 16), 256, 0, stream>>>(flg, x_bf, 2560, h_bf, DD,
                                                         wih, whh, bih, bhh,
                                                         2048, 0, gates, nullptr, nullptr, 0);
        dec_lstm_kernel<<<BB, 512, 0, stream>>>(gates, h_bf, c, lengths, t);
        // preds = h @ fc_w + fc_b (masked) : (64, 20000)
        gemm_m64_kernel<<<dim3(1, 157), 256, 0, stream>>>(flg, h_bf, DD, nullptr, 0,
                                                          fcw, nullptr, fcb, nullptr,
                                                          VV, 2, nullptr, d_out, lengths, t);
    }
}

// Round 4
// 3107.026 us; speedup vs baseline: 4.5357x; 1.7351x over previous
//
#include <hip/hip_runtime.h>

#define BB   64
#define PP   196
#define ENC  2048
#define AA   512
#define EE   512
#define DD   512
#define VV   20000
#define VVP  20096          // padded to 157*128
#define TT   21
#define ML   22

#define PRED_ELEMS ((size_t)BB * TT * VV)   // 26,880,000

typedef __attribute__((ext_vector_type(8))) short s8bf;    // 8 bf16 (4 VGPRs)
typedef __attribute__((ext_vector_type(4))) float f4acc;   // 4 fp32 acc

__device__ __forceinline__ float bf2f(unsigned short u) {
    union { unsigned int i; float f; } v; v.i = ((unsigned int)u) << 16; return v.f;
}
__device__ __forceinline__ void unpack2(unsigned int u, float& lo, float& hi) {
    union { unsigned int i; float f; } a, b;
    a.i = u << 16; b.i = u & 0xFFFF0000u; lo = a.f; hi = b.f;
}
__device__ __forceinline__ unsigned short f2bf(float f) {
    union { float f; unsigned int i; } v; v.f = f;
    unsigned int i = v.i;
    return (unsigned short)((i + 0x7FFFu + ((i >> 16) & 1u)) >> 16); // RNE
}
__device__ __forceinline__ float sigmoidf(float x) { return 1.0f / (1.0f + __expf(-x)); }

template <bool F> __device__ __forceinline__ float ldw(const void* p, size_t i) {
    if (F) return ((const float*)p)[i];
    return bf2f(((const unsigned short*)p)[i]);
}
template <bool F> __device__ __forceinline__ unsigned short ldbf(const void* p, size_t i) {
    if (F) return f2bf(((const float*)p)[i]);   // exact: values are bf16-quantized
    return ((const unsigned short*)p)[i];
}
template <bool F> __device__ __forceinline__ float2 ld2(const void* p, size_t i) {
    if (F) return *(const float2*)((const float*)p + i);
    unsigned int u = *(const unsigned int*)((const unsigned short*)p + i);
    float lo, hi; unpack2(u, lo, hi); return make_float2(lo, hi);
}
template <bool F> __device__ __forceinline__ float4 ld4(const void* p, size_t i) {
    if (F) return *(const float4*)((const float*)p + i);
    uint2 u = *(const uint2*)((const unsigned short*)p + i);
    float a, b, c, d; unpack2(u.x, a, b); unpack2(u.y, c, d);
    return make_float4(a, b, c, d);
}
template <bool F> __device__ __forceinline__ void st1(void* p, size_t i, float v) {
    if (F) ((float*)p)[i] = v; else ((unsigned short*)p)[i] = f2bf(v);
}

// ---------------- dtype detector ----------------
__global__ void dec_detect_kernel(const unsigned short* __restrict__ enc_us, int* __restrict__ flag) {
    __shared__ int s_cnt;
    if (threadIdx.x == 0) s_cnt = 0;
    __syncthreads();
    int cnt = 0;
    for (int i = threadIdx.x; i < 8192; i += 256) {
        unsigned short u = enc_us[2 * i];
        if ((u & 0x7F80) == 0x7F80) cnt++;
    }
    if (cnt) atomicAdd(&s_cnt, cnt);
    __syncthreads();
    if (threadIdx.x == 0) *flag = (s_cnt > 0) ? 1 : 0;
}

// ---------------- weight swizzle: W[K x N] -> bf16 [nt][kc][lane][8] ----------------
// B-fragment for mfma_16x16x32: lane=(quad*16+l15), element j -> W[kc*32+quad*8+j][nt*16+l15]
// permMode 1: LSTM gate interleave: n' -> orig col = gate*512 + dchunk*32 + dl
template <bool F>
__device__ __forceinline__ void conv_swz_body(const void* W, int K, int Norig,
                                              unsigned short* dst, int permMode, int nChunks) {
    int chunk = blockIdx.x * 4 + (threadIdx.x >> 6);
    if (chunk >= nChunks) return;
    int lane = threadIdx.x & 63;
    int KC = K >> 5;
    int nt = chunk / KC, kc = chunk % KC;
    int quad = lane >> 4, l15 = lane & 15;
    int np = nt * 16 + l15;
    int col;
    if (permMode == 1) col = ((np >> 5) & 3) * 512 + (np >> 7) * 32 + (np & 31);
    else col = np;
    union { s8bf v; unsigned short s[8]; } o;
    if (np < Norig || permMode == 1) {
        size_t base = (size_t)(kc * 32 + quad * 8) * Norig + col;
#pragma unroll
        for (int j = 0; j < 8; ++j) o.s[j] = ldbf<F>(W, base + (size_t)j * Norig);
    } else {
#pragma unroll
        for (int j = 0; j < 8; ++j) o.s[j] = 0;
    }
    *(s8bf*)(dst + ((size_t)chunk * 64 + lane) * 8) = o.v;
}
__global__ void conv_swz_kernel(const int* __restrict__ flg, const void* __restrict__ W,
                                int K, int Norig, unsigned short* __restrict__ dst,
                                int permMode, int nChunks) {
    if (*flg) conv_swz_body<true>(W, K, Norig, dst, permMode, nChunks);
    else      conv_swz_body<false>(W, K, Norig, dst, permMode, nChunks);
}

// ---------------- bias prep (all epilogue biases as f32) ----------------
template <bool F>
__device__ __forceinline__ void conv_bias_body(const void* dab, const void* fbb,
                                               const void* bih, const void* bhh, const void* fcb,
                                               const void* ihb, const void* icb, const void* eab,
                                               float* ag_b, float* g_b, float* fc_b,
                                               float* ihb_f, float* icb_f, float* eab_f) {
    int i = blockIdx.x * 256 + threadIdx.x;
    if (i < 2560) ag_b[i] = (i < 512) ? ldw<F>(dab, i) : ldw<F>(fbb, i - 512);
    else if (i < 2560 + 2048) {
        int np = i - 2560;
        int orig = ((np >> 5) & 3) * 512 + (np >> 7) * 32 + (np & 31);
        g_b[np] = ldw<F>(bih, orig) + ldw<F>(bhh, orig);
    } else if (i < 2560 + 2048 + 20000) fc_b[i - 4608] = ldw<F>(fcb, i - 4608);
    else if (i < 2560 + 2048 + 20000 + 512) ihb_f[i - 24608] = ldw<F>(ihb, i - 24608);
    else if (i < 2560 + 2048 + 20000 + 1024) icb_f[i - 25120] = ldw<F>(icb, i - 25120);
    else if (i < 2560 + 2048 + 20000 + 1536) eab_f[i - 25632] = ldw<F>(eab, i - 25632);
}
__global__ void conv_bias_kernel(const int* __restrict__ flg,
                                 const void* dab, const void* fbb, const void* bih, const void* bhh,
                                 const void* fcb, const void* ihb, const void* icb, const void* eab,
                                 float* ag_b, float* g_b, float* fc_b,
                                 float* ihb_f, float* icb_f, float* eab_f) {
    if (*flg) conv_bias_body<true>(dab, fbb, bih, bhh, fcb, ihb, icb, eab, ag_b, g_b, fc_b, ihb_f, icb_f, eab_f);
    else      conv_bias_body<false>(dab, fbb, bih, bhh, fcb, ihb, icb, eab, ag_b, g_b, fc_b, ihb_f, icb_f, eab_f);
}

// ---------------- mean over P -> bf16 ----------------
template <bool F>
__device__ __forceinline__ void mean_body(const void* enc, unsigned short* mean_bf) {
    int b = blockIdx.x;
    int e = blockIdx.y * 256 + threadIdx.x;
    size_t base = (size_t)b * PP * ENC + e;
    float s = 0.f;
#pragma unroll 4
    for (int p = 0; p < PP; ++p) s += ldw<F>(enc, base + (size_t)p * ENC);
    mean_bf[b * ENC + e] = f2bf(s * (1.0f / (float)PP));
}
__global__ void dec_mean_kernel(const void* __restrict__ enc, const int* __restrict__ flg,
                                unsigned short* __restrict__ mean_bf) {
    if (*flg) mean_body<true>(enc, mean_bf); else mean_body<false>(enc, mean_bf);
}

// ---------------- unified M=64 MFMA GEMM, swizzled-B, fused epilogues ----------------
// epi 0: outF[m*N+n] = v                   (c0)
// epi 1: n<512 -> att2f[m*512+n]=v ; else gatef[m*2048+n-512]=sigmoid(v)
// epi 2: preds masked -> outV (dtype by *flg) at (m*TT+t)*VV+n
// epi 3: h_bf[m*512+n] = bf16(v)           (h0)
// epi 4: gates (perm cols) + fused LSTM: update cptr, hb
__global__ __launch_bounds__(256)
void gemm_u_kernel(const int* __restrict__ flg,
                   const unsigned short* __restrict__ A1, int K1, const unsigned short* __restrict__ W1,
                   const unsigned short* __restrict__ A2, int K2, const unsigned short* __restrict__ W2,
                   const float* __restrict__ bias, int N, int epi,
                   float* __restrict__ outF, float* __restrict__ outF2,
                   unsigned short* __restrict__ hb, float* __restrict__ cptr,
                   void* __restrict__ outV, const int* __restrict__ lengths, int t) {
    __shared__ float s_g[4 * 64 * 32];                 // 32 KB, used by epi 4
    int tid = threadIdx.x;
    int wave = tid >> 6, lane = tid & 63;
    int l15 = lane & 15, quad = lane >> 4;
    f4acc acc[4][2];
#pragma unroll
    for (int a = 0; a < 4; ++a) { acc[a][0] = (f4acc)0.f; acc[a][1] = (f4acc)0.f; }
#pragma unroll
    for (int pass = 0; pass < 2; ++pass) {
        const unsigned short* A = pass ? A2 : A1;
        if (!A) continue;
        int K = pass ? K2 : K1;
        const unsigned short* W = pass ? W2 : W1;
        int KC = K >> 5;
        for (int kc = 0; kc < KC; ++kc) {
            s8bf af[4];
#pragma unroll
            for (int rt = 0; rt < 4; ++rt)
                af[rt] = *(const s8bf*)(A + (size_t)(rt * 16 + l15) * K + kc * 32 + quad * 8);
#pragma unroll
            for (int ct = 0; ct < 2; ++ct) {
                int nt = blockIdx.y * 8 + ct * 4 + wave;
                s8bf bv = *(const s8bf*)(W + ((size_t)(nt * KC + kc) * 64 + lane) * 8);
#pragma unroll
                for (int rt = 0; rt < 4; ++rt)
                    acc[rt][ct] = __builtin_amdgcn_mfma_f32_16x16x32_bf16(af[rt], bv, acc[rt][ct], 0, 0, 0);
            }
        }
    }
    if (epi == 4) {
#pragma unroll
        for (int ct = 0; ct < 2; ++ct) {
            int nl = wave * 16 + ct * 64 + l15;        // 0..127 within block
            int g = nl >> 5, dl = nl & 31;
            float bv = bias[blockIdx.y * 128 + nl];
#pragma unroll
            for (int rt = 0; rt < 4; ++rt)
#pragma unroll
                for (int r = 0; r < 4; ++r) {
                    int m = rt * 16 + quad * 4 + r;
                    s_g[(g * 64 + m) * 32 + dl] = acc[rt][ct][r] + bv;
                }
        }
        __syncthreads();
        int m = tid >> 2;
        bool act = t < (lengths[m] - 1);
        if (act) {
#pragma unroll
            for (int i = 0; i < 8; ++i) {
                int dl = (tid & 3) * 8 + i;
                int d = blockIdx.y * 32 + dl;
                float ig = sigmoidf(s_g[(0 * 64 + m) * 32 + dl]);
                float fg = sigmoidf(s_g[(1 * 64 + m) * 32 + dl]);
                float gg = tanhf(s_g[(2 * 64 + m) * 32 + dl]);
                float og = sigmoidf(s_g[(3 * 64 + m) * 32 + dl]);
                float cn = fg * cptr[m * DD + d] + ig * gg;
                float hn = og * tanhf(cn);
                cptr[m * DD + d] = cn;
                hb[m * DD + d] = f2bf(hn);
            }
        }
        return;
    }
    bool f32o = (epi == 2) ? (*flg != 0) : false;
#pragma unroll
    for (int ct = 0; ct < 2; ++ct) {
        int n = blockIdx.y * 128 + ct * 64 + wave * 16 + l15;
        if (n >= N) continue;
        float bv = bias ? bias[n] : 0.f;
#pragma unroll
        for (int rt = 0; rt < 4; ++rt)
#pragma unroll
            for (int r = 0; r < 4; ++r) {
                int m = rt * 16 + quad * 4 + r;
                float v = acc[rt][ct][r] + bv;
                if (epi == 0)      outF[(size_t)m * N + n] = v;
                else if (epi == 1) {
                    if (n < 512) outF[(size_t)m * 512 + n] = v;
                    else         outF2[(size_t)m * 2048 + (n - 512)] = sigmoidf(v);
                } else if (epi == 3) hb[(size_t)m * DD + n] = f2bf(v);
                else {             // epi 2: preds
                    bool act = t < (lengths[m] - 1);
                    float pv = act ? v : 0.f;
                    size_t oi = ((size_t)m * TT + t) * VV + n;
                    if (f32o) ((float*)outV)[oi] = pv; else ((unsigned short*)outV)[oi] = f2bf(pv);
                }
            }
    }
}

// ---------------- att1: MFMA GEMM (M=12544, N=512, K=2048), swizzled B ----------------
template <bool F>
__device__ __forceinline__ void att1_gemm_body(const void* enc, const unsigned short* Wsw,
                                               const float* bias, float* att1) {
    __shared__ __attribute__((aligned(16))) unsigned short As[64 * 40];
    int tid = threadIdx.x;
    int wave = tid >> 6, lane = tid & 63;
    int l15 = lane & 15, quad = lane >> 4;
    int row0 = blockIdx.x * 64;
    f4acc acc[4][2];
#pragma unroll
    for (int a = 0; a < 4; ++a) { acc[a][0] = (f4acc)0.f; acc[a][1] = (f4acc)0.f; }
    int lr = tid >> 2, lk = (tid & 3) * 8;
    for (int kc = 0; kc < 64; ++kc) {
        int k0 = kc * 32;
        if (F) {
            const float* src = (const float*)enc + (size_t)(row0 + lr) * ENC + k0 + lk;
            float4 v0 = *(const float4*)src, v1 = *(const float4*)(src + 4);
            union { s8bf v; unsigned short s[8]; } t8;
            t8.s[0]=f2bf(v0.x); t8.s[1]=f2bf(v0.y); t8.s[2]=f2bf(v0.z); t8.s[3]=f2bf(v0.w);
            t8.s[4]=f2bf(v1.x); t8.s[5]=f2bf(v1.y); t8.s[6]=f2bf(v1.z); t8.s[7]=f2bf(v1.w);
            *(s8bf*)&As[lr * 40 + lk] = t8.v;
        } else {
            *(s8bf*)&As[lr * 40 + lk] =
                *(const s8bf*)((const unsigned short*)enc + (size_t)(row0 + lr) * ENC + k0 + lk);
        }
        __syncthreads();
        s8bf af[4];
#pragma unroll
        for (int rt = 0; rt < 4; ++rt)
            af[rt] = *(const s8bf*)&As[(rt * 16 + l15) * 40 + quad * 8];
#pragma unroll
        for (int ct = 0; ct < 2; ++ct) {
            int nt = blockIdx.y * 8 + ct * 4 + wave;
            s8bf bv = *(const s8bf*)(Wsw + ((size_t)(nt * 64 + kc) * 64 + lane) * 8);
#pragma unroll
            for (int rt = 0; rt < 4; ++rt)
                acc[rt][ct] = __builtin_amdgcn_mfma_f32_16x16x32_bf16(af[rt], bv, acc[rt][ct], 0, 0, 0);
        }
        __syncthreads();
    }
#pragma unroll
    for (int ct = 0; ct < 2; ++ct) {
        int n = blockIdx.y * 128 + ct * 64 + wave * 16 + l15;
        float bv = bias[n];
#pragma unroll
        for (int rt = 0; rt < 4; ++rt)
#pragma unroll
            for (int r = 0; r < 4; ++r) {
                int m = row0 + rt * 16 + quad * 4 + r;
                att1[(size_t)m * AA + n] = acc[rt][ct][r] + bv;
            }
    }
}
__global__ __launch_bounds__(256)
void gemm_att1_kernel(const void* __restrict__ enc, const int* __restrict__ flg,
                      const unsigned short* __restrict__ Wsw, const float* __restrict__ bias,
                      float* __restrict__ att1) {
    if (*flg) att1_gemm_body<true>(enc, Wsw, bias, att1);
    else      att1_gemm_body<false>(enc, Wsw, bias, att1);
}

// ---------------- scores + softmax ----------------
template <bool F>
__device__ __forceinline__ void att_body(const float* att1, const float* att2,
                                         const void* faw, const void* fab,
                                         const int* lengths, float* alpha_ws, void* out, int t) {
    __shared__ float s_att2[AA];
    __shared__ float s_fw[AA];
    __shared__ float s_red[256];
    int b = blockIdx.x, tid = threadIdx.x;
    for (int a = tid; a < AA; a += 256) { s_att2[a] = att2[b * AA + a]; s_fw[a] = ldw<F>(faw, a); }
    __syncthreads();
    float sc = -1e30f;
    if (tid < PP) {
        const float4* r = (const float4*)(att1 + (size_t)(b * PP + tid) * AA);
        float acc = 0.f;
#pragma unroll 4
        for (int a4 = 0; a4 < AA / 4; ++a4) {
            float4 v = r[a4];
            int a = a4 * 4;
            acc += fmaxf(v.x + s_att2[a], 0.f)     * s_fw[a]
                 + fmaxf(v.y + s_att2[a + 1], 0.f) * s_fw[a + 1]
                 + fmaxf(v.z + s_att2[a + 2], 0.f) * s_fw[a + 2]
                 + fmaxf(v.w + s_att2[a + 3], 0.f) * s_fw[a + 3];
        }
        sc = acc + ldw<F>(fab, 0);
    }
    s_red[tid] = sc;
    __syncthreads();
    for (int s = 128; s > 0; s >>= 1) { if (tid < s) s_red[tid] = fmaxf(s_red[tid], s_red[tid + s]); __syncthreads(); }
    float m = s_red[0];
    __syncthreads();
    float e = 0.f;
    if (tid < PP) e = __expf(sc - m);
    s_red[tid] = e;
    __syncthreads();
    for (int s = 128; s > 0; s >>= 1) { if (tid < s) s_red[tid] += s_red[tid + s]; __syncthreads(); }
    float inv = 1.0f / s_red[0];
    if (tid < PP) {
        float al = e * inv;
        alpha_ws[b * PP + tid] = al;
        bool active = t < (lengths[b] - 1);
        st1<F>(out, PRED_ELEMS + (size_t)(b * TT + t) * PP + tid, active ? al : 0.f);
    }
}
__global__ void dec_att_kernel(const float* __restrict__ att1, const float* __restrict__ att2,
                               const int* __restrict__ flg,
                               const void* __restrict__ faw, const void* __restrict__ fab,
                               const int* __restrict__ lengths,
                               float* __restrict__ alpha_ws, void* __restrict__ out, int t) {
    if (*flg) att_body<true>(att1, att2, faw, fab, lengths, alpha_ws, out, t);
    else      att_body<false>(att1, att2, faw, fab, lengths, alpha_ws, out, t);
}

// ---------------- context partial sums ----------------
template <bool F>
__device__ __forceinline__ void ctx_partial_body(const void* enc, const float* alpha_ws, float* partial) {
    __shared__ float s_al[PP];
    int b = blockIdx.x, half = blockIdx.y, pc = blockIdx.z, tid = threadIdx.x; // grid (64,2,4)
    if (tid < PP) s_al[tid] = alpha_ws[b * PP + tid];
    __syncthreads();
    int e = half * 1024 + tid * 4;
    float a0 = 0.f, a1 = 0.f, a2 = 0.f, a3 = 0.f;
    int p0 = pc * 49;
#pragma unroll 4
    for (int p = p0; p < p0 + 49; ++p) {
        float al = s_al[p];
        float4 v = ld4<F>(enc, (size_t)(b * PP + p) * ENC + e);
        a0 += al * v.x; a1 += al * v.y; a2 += al * v.z; a3 += al * v.w;
    }
    *(float4*)&partial[(size_t)(b * 4 + pc) * ENC + e] = make_float4(a0, a1, a2, a3);
}
__global__ void dec_ctx_partial_kernel(const void* __restrict__ enc, const int* __restrict__ flg,
                                       const float* __restrict__ alpha_ws, float* __restrict__ partial) {
    if (*flg) ctx_partial_body<true>(enc, alpha_ws, partial);
    else      ctx_partial_body<false>(enc, alpha_ws, partial);
}

// ---------------- reduce + gate + assemble x_bf ----------------
template <bool F>
__device__ __forceinline__ void ctx_reduce_body(const float* partial, const float* gate,
                                                const void* emb, const int* captions,
                                                unsigned short* x_bf, int t) {
    int b = blockIdx.x, half = blockIdx.y, tid = threadIdx.x;  // grid (64,2), block 256
    if (half == 0) {
        int cap = captions[b * ML + t];
        int i = tid * 2;
        float2 ev = ld2<F>(emb, (size_t)cap * EE + i);
        *(unsigned int*)(x_bf + (size_t)b * 2560 + i) =
            (unsigned int)f2bf(ev.x) | ((unsigned int)f2bf(ev.y) << 16);
    }
    int e = half * 1024 + tid * 4;
    float4 s = *(const float4*)&partial[(size_t)(b * 4 + 0) * ENC + e];
#pragma unroll
    for (int pc = 1; pc < 4; ++pc) {
        float4 v = *(const float4*)&partial[(size_t)(b * 4 + pc) * ENC + e];
        s.x += v.x; s.y += v.y; s.z += v.z; s.w += v.w;
    }
    float4 g = *(const float4*)&gate[(size_t)b * ENC + e];
    uint2 pk;
    pk.x = (unsigned int)f2bf(s.x * g.x) | ((unsigned int)f2bf(s.y * g.y) << 16);
    pk.y = (unsigned int)f2bf(s.z * g.z) | ((unsigned int)f2bf(s.w * g.w) << 16);
    *(uint2*)(x_bf + (size_t)b * 2560 + EE + e) = pk;
}
__global__ void dec_ctx_reduce_kernel(const float* __restrict__ partial, const float* __restrict__ gate,
                                      const int* __restrict__ flg,
                                      const void* __restrict__ emb, const int* __restrict__ captions,
                                      unsigned short* __restrict__ x_bf, int t) {
    if (*flg) ctx_reduce_body<true>(partial, gate, emb, captions, x_bf, t);
    else      ctx_reduce_body<false>(partial, gate, emb, captions, x_bf, t);
}

extern "C" void kernel_launch(void* const* d_in, const int* in_sizes, int n_in,
                              void* d_out, int out_size, void* d_ws, size_t ws_size,
                              hipStream_t stream) {
    const void* enc      = d_in[0];
    const int* captions  = (const int*)d_in[1];
    const int* lengths   = (const int*)d_in[2];
    const void* emb      = d_in[3];
    const void* eaw      = d_in[4];
    const void* eab      = d_in[5];
    const void* daw      = d_in[6];
    const void* dab      = d_in[7];
    const void* faw      = d_in[8];
    const void* fab      = d_in[9];
    const void* wih      = d_in[10];
    const void* bih      = d_in[11];
    const void* whh      = d_in[12];
    const void* bhh      = d_in[13];
    const void* ihw      = d_in[14];
    const void* ihb      = d_in[15];
    const void* icw      = d_in[16];
    const void* icb      = d_in[17];
    const void* fbw      = d_in[18];
    const void* fbb      = d_in[19];
    const void* fcw      = d_in[20];
    const void* fcb      = d_in[21];

    char* cur = (char*)d_ws;
    auto alloc = [&](size_t bytes) { void* p = cur; cur += (bytes + 255) & ~(size_t)255; return p; };
    int* flg               = (int*)alloc(4);
    unsigned short* h_bf   = (unsigned short*)alloc((size_t)BB * DD * 2);
    unsigned short* x_bf   = (unsigned short*)alloc((size_t)BB * 2560 * 2);
    unsigned short* mean_bf= (unsigned short*)alloc((size_t)BB * ENC * 2);
    float* c               = (float*)alloc((size_t)BB * DD * 4);
    float* att2            = (float*)alloc((size_t)BB * AA * 4);
    float* gate            = (float*)alloc((size_t)BB * ENC * 4);
    float* alpha           = (float*)alloc((size_t)BB * PP * 4);
    float* partial         = (float*)alloc((size_t)BB * 4 * ENC * 4);
    float* ag_bias         = (float*)alloc(2560 * 4);
    float* g_bias          = (float*)alloc(2048 * 4);
    float* fc_bias         = (float*)alloc(20000 * 4);
    float* ihb_f           = (float*)alloc(512 * 4);
    float* icb_f           = (float*)alloc(512 * 4);
    float* eab_f           = (float*)alloc(512 * 4);
    unsigned short* eaw_sw = (unsigned short*)alloc((size_t)32 * 64 * 512 * 2);       // 2.1 MB
    unsigned short* ag_sw  = (unsigned short*)alloc((size_t)160 * 16 * 512 * 2);      // 2.6 MB
    unsigned short* ihw_sw = (unsigned short*)alloc((size_t)32 * 64 * 512 * 2);
    unsigned short* icw_sw = (unsigned short*)alloc((size_t)32 * 64 * 512 * 2);
    unsigned short* wih_sw = (unsigned short*)alloc((size_t)128 * 80 * 512 * 2);      // 10.5 MB
    unsigned short* whh_sw = (unsigned short*)alloc((size_t)128 * 16 * 512 * 2);      // 2.1 MB
    unsigned short* fcw_sw = (unsigned short*)alloc((size_t)1256 * 16 * 512 * 2);     // 20.6 MB
    float* att1            = (float*)alloc((size_t)BB * PP * AA * 4);                 // 25.7 MB

    dec_detect_kernel<<<1, 256, 0, stream>>>((const unsigned short*)enc, flg);
    // weight swizzles: chunks = (Npad/16)*(K/32), 4 chunks per block
    conv_swz_kernel<<<(32 * 64 + 3) / 4, 256, 0, stream>>>(flg, eaw, ENC, AA, eaw_sw, 0, 32 * 64);
    conv_swz_kernel<<<(32 * 16 + 3) / 4, 256, 0, stream>>>(flg, daw, DD, AA, ag_sw, 0, 32 * 16);
    conv_swz_kernel<<<(128 * 16 + 3) / 4, 256, 0, stream>>>(flg, fbw, DD, ENC, ag_sw + (size_t)32 * 16 * 512, 0, 128 * 16);
    conv_swz_kernel<<<(32 * 64 + 3) / 4, 256, 0, stream>>>(flg, ihw, ENC, DD, ihw_sw, 0, 32 * 64);
    conv_swz_kernel<<<(32 * 64 + 3) / 4, 256, 0, stream>>>(flg, icw, ENC, DD, icw_sw, 0, 32 * 64);
    conv_swz_kernel<<<(128 * 80 + 3) / 4, 256, 0, stream>>>(flg, wih, 2560, 2048, wih_sw, 1, 128 * 80);
    conv_swz_kernel<<<(128 * 16 + 3) / 4, 256, 0, stream>>>(flg, whh, DD, 2048, whh_sw, 1, 128 * 16);
    conv_swz_kernel<<<(1256 * 16 + 3) / 4, 256, 0, stream>>>(flg, fcw, DD, VV, fcw_sw, 0, 1256 * 16);
    conv_bias_kernel<<<(26144 + 255) / 256, 256, 0, stream>>>(flg, dab, fbb, bih, bhh, fcb, ihb, icb, eab,
                                                              ag_bias, g_bias, fc_bias, ihb_f, icb_f, eab_f);
    dec_mean_kernel<<<dim3(BB, ENC / 256), 256, 0, stream>>>(enc, flg, mean_bf);
    // h0, c0 via MFMA
    gemm_u_kernel<<<dim3(1, 4), 256, 0, stream>>>(flg, mean_bf, ENC, ihw_sw, nullptr, 0, nullptr,
                                                  ihb_f, DD, 3, nullptr, nullptr, h_bf, nullptr, nullptr, nullptr, 0);
    gemm_u_kernel<<<dim3(1, 4), 256, 0, stream>>>(flg, mean_bf, ENC, icw_sw, nullptr, 0, nullptr,
                                                  icb_f, DD, 0, c, nullptr, nullptr, nullptr, nullptr, nullptr, 0);
    gemm_att1_kernel<<<dim3(196, 4), 256, 0, stream>>>(enc, flg, eaw_sw, eab_f, att1);

    for (int t = 0; t < TT; ++t) {
        // att2 (cols 0..511) + f_beta gate (cols 512..2559), fused
        gemm_u_kernel<<<dim3(1, 20), 256, 0, stream>>>(flg, h_bf, DD, ag_sw, nullptr, 0, nullptr,
                                                       ag_bias, 2560, 1, att2, gate, nullptr, nullptr, nullptr, nullptr, 0);
        dec_att_kernel<<<BB, 256, 0, stream>>>(att1, att2, flg, faw, fab, lengths, alpha, d_out, t);
        dec_ctx_partial_kernel<<<dim3(BB, 2, 4), 256, 0, stream>>>(enc, flg, alpha, partial);
        dec_ctx_reduce_kernel<<<dim3(BB, 2), 256, 0, stream>>>(partial, gate, flg, emb, captions, x_bf, t);
        // gates GEMM + fused LSTM pointwise (gate-interleaved columns)
        gemm_u_kernel<<<dim3(1, 16), 256, 0, stream>>>(flg, x_bf, 2560, wih_sw, h_bf, DD, whh_sw,
                                                       g_bias, 2048, 4, nullptr, nullptr, h_bf, c, nullptr, lengths, t);
        // preds
        gemm_u_kernel<<<dim3(1, 157), 256, 0, stream>>>(flg, h_bf, DD, fcw_sw, nullptr, 0, nullptr,
                                                        fc_bias, VV, 2, nullptr, nullptr, nullptr, nullptr, d_out, lengths, t);
    }
}